// Round 1
// baseline (63.645 us; speedup 1.0000x reference)
//
#include <hip/hip_runtime.h>
#include <hip/hip_bf16.h>

typedef float f32x4 __attribute__((ext_vector_type(4)));
typedef short bf16x8 __attribute__((ext_vector_type(8)));
typedef unsigned short u16;

#define NB 32
#define NN 10000
#define DIMX 64

__device__ __forceinline__ u16 f2bf(float f) {
    union { float f; unsigned u; } v; v.f = f;
    unsigned r = (v.u + 0x7FFFu + ((v.u >> 16) & 1u)) >> 16;
    return (u16)r;
}

// ---------------- K1: prep ----------------
// bias1[b][j] = n2e_b[j] + sum_d x[b,i,d] * n2e_w[j][64+d]   (fp32)
// w1p: bf16 fragment-packed n2e_w[:, :64]  (t<8, kk<2, lane<64, i<8)
// w2p: bf16 fragment-packed e2e_w          (t<8, kk<4, lane<64, i<8)
__global__ void k_prep(const float* __restrict__ x, const float* __restrict__ n2e_w,
                       const float* __restrict__ n2e_b, const float* __restrict__ e2e_w,
                       const int* __restrict__ ip,
                       float* __restrict__ bias1, u16* __restrict__ w1p, u16* __restrict__ w2p) {
    int id = blockIdx.x * 256 + threadIdx.x;
    if (id < 4096) {
        int b = id >> 7, j = id & 127;
        int i = ip[0];
        const float* xr = x + ((size_t)b * NN + i) * DIMX;
        const float* w = n2e_w + j * 128 + 64;
        float s = n2e_b[j];
        #pragma unroll
        for (int d = 0; d < 64; ++d) s += xr[d] * w[d];
        bias1[b * 128 + j] = s;
    } else if (id < 12288) {
        int e = id - 4096;
        int i8 = e & 7, lane = (e >> 3) & 63, kk = (e >> 9) & 1, t = e >> 10;
        int row = t * 16 + (lane & 15), col = kk * 32 + (lane >> 4) * 8 + i8;
        w1p[e] = f2bf(n2e_w[row * 128 + col]);
    } else if (id < 28672) {
        int e = id - 12288;
        int i8 = e & 7, lane = (e >> 3) & 63, kk = (e >> 9) & 3, t = e >> 11;
        int row = t * 16 + (lane & 15), col = kk * 32 + (lane >> 4) * 8 + i8;
        w2p[e] = f2bf(e2e_w[row * 128 + col]);
    }
}

// ---------------- K2: main fused GEMM1+GEMM2+reduce ----------------
// grid = 256 blocks (b = bid>>3, q = bid&7), 4 waves/block.
// Each wave per iteration: 4 subtiles x 16 rows. 5 iterations.
__global__ __launch_bounds__(256, 1) void k_main(
        const float* __restrict__ x, const float* __restrict__ adj,
        const float* __restrict__ bias1, const u16* __restrict__ w1p,
        const u16* __restrict__ w2p, const float* __restrict__ e2e_b,
        float* __restrict__ partials) {
    __shared__ u16 sW1[8192];    // 16 KB
    __shared__ u16 sW2[16384];   // 32 KB
    __shared__ u16 sH1[8192];    // 16 KB: 4 waves * 4 subs * (16 rows x 32 cols)
    const int tid = threadIdx.x;
    const int lane = tid & 63, wave = tid >> 6;
    const int c = lane & 15, g = lane >> 4;
    const int bid = blockIdx.x, b = bid >> 3, q = bid & 7;

    // stage packed weights into LDS (linear, conflict-free)
    #pragma unroll
    for (int p = 0; p < 4; ++p) { int o = (p * 256 + tid) * 8;
        *(bf16x8*)&sW1[o] = *(const bf16x8*)&w1p[o]; }
    #pragma unroll
    for (int p = 0; p < 8; ++p) { int o = (p * 256 + tid) * 8;
        *(bf16x8*)&sW2[o] = *(const bf16x8*)&w2p[o]; }

    float bias1v[8], b2v[8];
    #pragma unroll
    for (int t = 0; t < 8; ++t) {
        bias1v[t] = bias1[b * 128 + t * 16 + c];
        b2v[t]    = e2e_b[t * 16 + c];
    }
    float sAcc[8] = {0.f,0.f,0.f,0.f,0.f,0.f,0.f,0.f};
    __syncthreads();

    for (int it = 0; it < 5; ++it) {
        const int n0 = (q * 80 + it * 16 + wave * 4) * 16;
        bf16x8 A1[4][2];
        f32x4 adj4[4];
        #pragma unroll
        for (int sub = 0; sub < 4; ++sub) {
            int ns = n0 + sub * 16;
            int nr = ns + c; nr = nr < NN ? nr : NN - 1;
            const float* xr = x + ((size_t)b * NN + nr) * DIMX + g * 8;
            #pragma unroll
            for (int kk = 0; kk < 2; ++kk) {
                f32x4 lo = *(const f32x4*)(xr + kk * 32);
                f32x4 hi = *(const f32x4*)(xr + kk * 32 + 4);
                bf16x8 a;
                a[0]=(short)f2bf(lo[0]); a[1]=(short)f2bf(lo[1]);
                a[2]=(short)f2bf(lo[2]); a[3]=(short)f2bf(lo[3]);
                a[4]=(short)f2bf(hi[0]); a[5]=(short)f2bf(hi[1]);
                a[6]=(short)f2bf(hi[2]); a[7]=(short)f2bf(hi[3]);
                A1[sub][kk] = a;
            }
            int r0 = ns + 4 * g;
            if (r0 + 3 < NN) adj4[sub] = *(const f32x4*)(adj + r0);
            else {
                #pragma unroll
                for (int k = 0; k < 4; ++k) adj4[sub][k] = (r0 + k < NN) ? adj[r0 + k] : 0.0f;
            }
        }

        f32x4 acc2[4][8];
        #pragma unroll
        for (int s2 = 0; s2 < 4; ++s2)
            #pragma unroll
            for (int t2 = 0; t2 < 8; ++t2) acc2[s2][t2] = (f32x4){0.f,0.f,0.f,0.f};

        #pragma unroll
        for (int kk2 = 0; kk2 < 4; ++kk2) {
            // GEMM1 for j1 columns [32*kk2, 32*kk2+32): t = 2*kk2+dt
            #pragma unroll
            for (int dt = 0; dt < 2; ++dt) {
                const int t = kk2 * 2 + dt;
                bf16x8 b1a = *(const bf16x8*)&sW1[((t * 2 + 0) * 64 + lane) * 8];
                bf16x8 b1b = *(const bf16x8*)&sW1[((t * 2 + 1) * 64 + lane) * 8];
                #pragma unroll
                for (int sub = 0; sub < 4; ++sub) {
                    f32x4 a = {0.f,0.f,0.f,0.f};
                    a = __builtin_amdgcn_mfma_f32_16x16x32_bf16(A1[sub][0], b1a, a, 0, 0, 0);
                    a = __builtin_amdgcn_mfma_f32_16x16x32_bf16(A1[sub][1], b1b, a, 0, 0, 0);
                    // epilogue: bias + relu -> bf16 -> swizzled LDS slice
                    #pragma unroll
                    for (int r = 0; r < 4; ++r) {
                        float v = fmaxf(a[r] + bias1v[t], 0.0f);
                        int row = 4 * g + r;                    // n-row within subtile
                        int gj = 2 * dt + (c >> 3);             // jrel>>3
                        int off = (wave * 4 + sub) * 512 + row * 32
                                  + ((gj ^ g) << 3) + (c & 7);  // swizzle: ^ (row>>2)&3 == g
                        sH1[off] = f2bf(v);
                    }
                }
            }
            // GEMM2 partial-K: A2 fragments from swizzled slice
            bf16x8 A2[4];
            #pragma unroll
            for (int sub = 0; sub < 4; ++sub) {
                int off = (wave * 4 + sub) * 512 + c * 32 + ((g ^ ((c >> 2) & 3)) << 3);
                A2[sub] = *(const bf16x8*)&sH1[off];
            }
            #pragma unroll
            for (int t2 = 0; t2 < 8; ++t2) {
                bf16x8 b2f = *(const bf16x8*)&sW2[((t2 * 4 + kk2) * 64 + lane) * 8];
                #pragma unroll
                for (int sub = 0; sub < 4; ++sub)
                    acc2[sub][t2] = __builtin_amdgcn_mfma_f32_16x16x32_bf16(A2[sub], b2f, acc2[sub][t2], 0, 0, 0);
            }
        }
        // epilogue: bias2 + relu, adj-weighted row sum into sAcc
        #pragma unroll
        for (int sub = 0; sub < 4; ++sub)
            #pragma unroll
            for (int t2 = 0; t2 < 8; ++t2)
                #pragma unroll
                for (int r = 0; r < 4; ++r) {
                    float v = fmaxf(acc2[sub][t2][r] + b2v[t2], 0.0f);
                    sAcc[t2] = fmaf(adj4[sub][r], v, sAcc[t2]);
                }
    }

    // reduce over the 4 lane-groups (rows), then across waves
    #pragma unroll
    for (int t2 = 0; t2 < 8; ++t2) {
        float v = sAcc[t2];
        v += __shfl_xor(v, 16, 64);
        v += __shfl_xor(v, 32, 64);
        sAcc[t2] = v;
    }
    __syncthreads();
    float* sRed = (float*)sH1;
    if (lane < 16) {
        #pragma unroll
        for (int t2 = 0; t2 < 8; ++t2) sRed[wave * 128 + t2 * 16 + lane] = sAcc[t2];
    }
    __syncthreads();
    if (tid < 128)
        partials[bid * 128 + tid] = sRed[tid] + sRed[128 + tid] + sRed[256 + tid] + sRed[384 + tid];
}

// ---------------- K3: final small MLP ----------------
__global__ void k_final(const float* __restrict__ partials, const float* __restrict__ x,
                        const int* __restrict__ ip,
                        const float* __restrict__ e2n_w, const float* __restrict__ e2n_b,
                        const float* __restrict__ n2n_w, const float* __restrict__ n2n_b,
                        const float* __restrict__ out_w, const float* __restrict__ out_b,
                        float* __restrict__ out) {
    int b = blockIdx.x, j = threadIdx.x;  // 128 threads
    __shared__ float s0[128], s1[128], s2[128];
    float acc = 0.f;
    #pragma unroll
    for (int qq = 0; qq < 8; ++qq) acc += partials[(b * 8 + qq) * 128 + j];
    s0[j] = acc;
    __syncthreads();
    {
        float a1 = e2n_b[j];
        const float* w = e2n_w + j * 128;
        #pragma unroll 8
        for (int k = 0; k < 128; ++k) a1 += w[k] * s0[k];
        s1[j] = fmaxf(a1, 0.f);
    }
    __syncthreads();
    {
        float a2 = n2n_b[j];
        const float* w = n2n_w + j * 128;
        #pragma unroll 8
        for (int k = 0; k < 128; ++k) a2 += w[k] * s1[k];
        s2[j] = fmaxf(a2, 0.f);
    }
    __syncthreads();
    if (j < 64) {
        int i = ip[0];
        const float* xr = x + ((size_t)b * NN + i) * DIMX;
        const float* ow = out_w + j * 192;
        float o = out_b[j];
        #pragma unroll 8
        for (int m = 0; m < 64; ++m) o += ow[m] * xr[m];
        #pragma unroll 8
        for (int m = 0; m < 128; ++m) o += ow[64 + m] * s2[m];
        out[b * 64 + j] = o;
    }
}

extern "C" void kernel_launch(void* const* d_in, const int* in_sizes, int n_in,
                              void* d_out, int out_size, void* d_ws, size_t ws_size,
                              hipStream_t stream) {
    const float* x      = (const float*)d_in[0];
    const float* adj    = (const float*)d_in[1];
    const float* n2e_w  = (const float*)d_in[2];
    const float* n2e_b  = (const float*)d_in[3];
    const float* e2e_w  = (const float*)d_in[4];
    const float* e2e_b  = (const float*)d_in[5];
    const float* e2n_w  = (const float*)d_in[6];
    const float* e2n_b  = (const float*)d_in[7];
    const float* n2n_w  = (const float*)d_in[8];
    const float* n2n_b  = (const float*)d_in[9];
    const float* out_w  = (const float*)d_in[10];
    const float* out_b  = (const float*)d_in[11];
    const int*   ip     = (const int*)d_in[12];
    float* out = (float*)d_out;

    char* ws = (char*)d_ws;
    float* bias1    = (float*)ws;               // 16384 B
    u16*   w1p      = (u16*)(ws + 16384);       // 16384 B
    u16*   w2p      = (u16*)(ws + 32768);       // 32768 B
    float* partials = (float*)(ws + 65536);     // 131072 B (256 blocks * 128 f32)

    k_prep<<<112, 256, 0, stream>>>(x, n2e_w, n2e_b, e2e_w, ip, bias1, w1p, w2p);
    k_main<<<256, 256, 0, stream>>>(x, adj, bias1, w1p, w2p, e2e_b, partials);
    k_final<<<32, 128, 0, stream>>>(partials, x, ip, e2n_w, e2n_b, n2n_w, n2n_b,
                                    out_w, out_b, out);
}